// Round 1
// 673.062 us; speedup vs baseline: 1.3214x; 1.3214x over previous
//
#include <hip/hip_runtime.h>
#include <stddef.h>
#include <stdint.h>

using u16 = unsigned short;
typedef __attribute__((ext_vector_type(8))) short short8;
typedef __attribute__((ext_vector_type(4))) float f32x4;

// ---------------------------------------------------------------------------
// Problem constants
// ---------------------------------------------------------------------------
constexpr int NQ = 8192, NI = 8192, NTT = 4096, DIM = 256, DOUT = 128;
constexpr int EQI = 262144, EIT = 131072, EB = EQI + EIT;
constexpr float BN_EPS = 1e-5f;

// ---------------------------------------------------------------------------
// Workspace byte offsets
// ---------------------------------------------------------------------------
constexpr size_t al(size_t x) { return (x + 255) & ~(size_t)255; }
constexpr size_t BO_FQW = 0;                                   // bf16 [NQ,256]
constexpr size_t BO_FTW = BO_FQW + (size_t)NQ * DIM * 2;       // bf16 [NTT,256] (contiguous after FQW)
constexpr size_t BO_FIW = al(BO_FTW + (size_t)NTT * DIM * 2);  // bf16 [NI,256]
constexpr size_t BO_CQ  = al(BO_FIW + (size_t)NI * DIM * 2);   // bf16 [NQ,512] concat
constexpr size_t BO_CI  = al(BO_CQ + (size_t)NQ * 512 * 2);    // bf16 [NI,512]
constexpr size_t BO_CT  = al(BO_CI + (size_t)NI * 512 * 2);    // bf16 [NTT,512]
constexpr size_t BO_LQ  = al(BO_CT + (size_t)NTT * 512 * 2);   // f32  [NQ,128]
constexpr size_t BO_LI  = al(BO_LQ + (size_t)NQ * DOUT * 4);
constexpr size_t BO_LT  = al(BO_LI + (size_t)NI * DOUT * 4);
constexpr size_t BO_EQB = al(BO_LT + (size_t)NTT * DOUT * 4);  // bf16 embed_q [NQ,128]
constexpr size_t BO_EIB = al(BO_EQB + (size_t)NQ * DOUT * 2);
constexpr size_t BO_ETB = al(BO_EIB + (size_t)NI * DOUT * 2);
constexpr size_t BO_EQQ = al(BO_ETB + (size_t)NTT * DOUT * 2); // bf16 embed_q@Q [NQ,128]
constexpr size_t BO_EIQ = al(BO_EQQ + (size_t)NQ * DOUT * 2);
constexpr size_t BO_WTR = al(BO_EIQ + (size_t)NI * DOUT * 2);  // bf16 W^T [256,256]
constexpr size_t BO_WXQ = al(BO_WTR + (size_t)DIM * DIM * 2);  // bf16 Wq [128,512]
constexpr size_t BO_WXI = al(BO_WXQ + (size_t)DOUT * 512 * 2);
constexpr size_t BO_WXT = al(BO_WXI + (size_t)DOUT * 512 * 2);
constexpr size_t BO_QTR = al(BO_WXT + (size_t)DOUT * 512 * 2); // bf16 Q^T [128,128]
constexpr size_t BO_STAT = al(BO_QTR + (size_t)DOUT * DOUT * 2);  // f32 1024
constexpr size_t BO_AOFF = al(BO_STAT + 1024 * 4);
constexpr size_t BO_ACUR = al(BO_AOFF + (size_t)(NQ + 1) * 4);
constexpr size_t BO_ACOL = al(BO_ACUR + (size_t)NQ * 4);
constexpr size_t BO_AVAL = al(BO_ACOL + (size_t)EQI * 4);
constexpr size_t BO_BOFF = al(BO_AVAL + (size_t)EQI * 4);
constexpr size_t BO_BCUR = al(BO_BOFF + (size_t)(NI + 1) * 4);
constexpr size_t BO_BCOL = al(BO_BCUR + (size_t)NI * 4);
constexpr size_t BO_BVAL = al(BO_BCOL + (size_t)EB * 4);
constexpr size_t BO_DOFF = al(BO_BVAL + (size_t)EB * 4);
constexpr size_t BO_DCUR = al(BO_DOFF + (size_t)(NTT + 1) * 4);
constexpr size_t BO_DCOL = al(BO_DCUR + (size_t)NTT * 4);
constexpr size_t BO_DVAL = al(BO_DCOL + (size_t)EIT * 4);

// ---------------------------------------------------------------------------
// bf16 helpers (RNE)
// ---------------------------------------------------------------------------
__device__ __forceinline__ u16 f2bf(float f) {
    union { float f; uint32_t u; } v;
    v.f = f;
    uint32_t u = v.u;
    u += 0x7FFFu + ((u >> 16) & 1u);
    return (u16)(u >> 16);
}
__device__ __forceinline__ float bf2f(u16 h) {
    union { uint32_t u; float f; } v;
    v.u = (uint32_t)h << 16;
    return v.f;
}

// ---------------------------------------------------------------------------
// Merged histogram over 4 edge-key segments
// ---------------------------------------------------------------------------
__global__ __launch_bounds__(256) void hist4_kernel(const int* __restrict__ k0, int E0, int* c0,
                                                    const int* __restrict__ k1, int E1, int* c1,
                                                    const int* __restrict__ k2, int E2, int* c2,
                                                    const int* __restrict__ k3, int E3, int* c3) {
    int idx = blockIdx.x * 256 + threadIdx.x;
    if (idx < E0) { atomicAdd(&c0[k0[idx]], 1); return; }
    idx -= E0;
    if (idx < E1) { atomicAdd(&c1[k1[idx]], 1); return; }
    idx -= E1;
    if (idx < E2) { atomicAdd(&c2[k2[idx]], 1); return; }
    idx -= E2;
    if (idx < E3) atomicAdd(&c3[k3[idx]], 1);
}

// ---------------------------------------------------------------------------
// 3 exclusive scans in one launch (block 0:A/NQ, 1:B/NI, 2:D/NTT).
// Wave shfl-scan: 4 barriers per 1024-chunk instead of ~23.
// Writes exclusive prefix into offs[0..n] and in-place into cnt (cursor).
// ---------------------------------------------------------------------------
__global__ __launch_bounds__(1024) void scan3_kernel(int* cA, int* oA, int* cB, int* oB,
                                                     int* cD, int* oD) {
    int* cnt; int* offs; int n;
    if (blockIdx.x == 0) { cnt = cA; offs = oA; n = NQ; }
    else if (blockIdx.x == 1) { cnt = cB; offs = oB; n = NI; }
    else { cnt = cD; offs = oD; n = NTT; }
    __shared__ int swv[16];
    __shared__ int s_carry;
    const int t = threadIdx.x;
    const int lane = t & 63, wv = t >> 6;
    if (t == 0) s_carry = 0;
    __syncthreads();
    for (int base = 0; base < n; base += 1024) {
        int v = (base + t < n) ? cnt[base + t] : 0;
        int x = v;
#pragma unroll
        for (int off = 1; off < 64; off <<= 1) {
            int y = __shfl_up(x, off, 64);
            if (lane >= off) x += y;
        }
        if (lane == 63) swv[wv] = x;
        __syncthreads();
        if (wv == 0 && lane < 16) {
            int ws = swv[lane];
#pragma unroll
            for (int off = 1; off < 16; off <<= 1) {
                int y = __shfl_up(ws, off, 16);
                if ((lane & 15) >= off) ws += y;
            }
            swv[lane] = ws;
        }
        __syncthreads();
        const int carry = s_carry;
        const int incl = carry + ((wv > 0) ? swv[wv - 1] : 0) + x;
        if (base + t < n) {
            offs[base + t] = incl - v;
            cnt[base + t] = incl - v;
        }
        __syncthreads();
        if (t == 1023) s_carry = incl;
        __syncthreads();
    }
    if (t == 0) offs[n] = s_carry;
}

// ---------------------------------------------------------------------------
// Merged scatter over 4 segments
// ---------------------------------------------------------------------------
struct Scat {
    const int* key; const int* oth; const float* val;
    int E, coff;
    int* cur; int* col; float* sv;
};
struct ScatDesc { Scat s0, s1, s2, s3; };

__global__ __launch_bounds__(256) void scatter4_kernel(ScatDesc d) {
    int idx = blockIdx.x * 256 + threadIdx.x;
    Scat sg;
    if (idx < d.s0.E) sg = d.s0;
    else if ((idx -= d.s0.E) < d.s1.E) sg = d.s1;
    else if ((idx -= d.s1.E) < d.s2.E) sg = d.s2;
    else if ((idx -= d.s2.E) < d.s3.E) sg = d.s3;
    else return;
    int p = atomicAdd(&sg.cur[sg.key[idx]], 1);
    sg.col[p] = sg.oth[idx] + sg.coff;
    sg.sv[p] = sg.val[idx];
}

// ---------------------------------------------------------------------------
// Merged CSR SPMM over 3 segments: Y[r, 0:256] = relu(sum_j val[j]*X[col[j],:])
// One wave per row (4 rows/block); lane owns 4 consecutive bf16 (8B ushort4
// gather -> 512B/edge in one wave instruction). 4-edge software pipeline.
// Per-element accumulation order identical to the previous serial version.
// Y leading dim = 512 (left half of concat buffer).
// ---------------------------------------------------------------------------
__global__ __launch_bounds__(256) void spmm3_kernel(
    const int* __restrict__ offs0, const int* __restrict__ cols0, const float* __restrict__ vals0,
    const u16* __restrict__ X0, u16* __restrict__ Y0, int nb0,
    const int* __restrict__ offs1, const int* __restrict__ cols1, const float* __restrict__ vals1,
    const u16* __restrict__ X1, u16* __restrict__ Y1, int nb1,
    const int* __restrict__ offs2, const int* __restrict__ cols2, const float* __restrict__ vals2,
    const u16* __restrict__ X2, u16* __restrict__ Y2) {
    int b = blockIdx.x;
    const int* offs; const int* cols; const float* vals; const u16* X; u16* Y;
    if (b < nb0) { offs = offs0; cols = cols0; vals = vals0; X = X0; Y = Y0; }
    else if ((b -= nb0) < nb1) { offs = offs1; cols = cols1; vals = vals1; X = X1; Y = Y1; }
    else { b -= nb1; offs = offs2; cols = cols2; vals = vals2; X = X2; Y = Y2; }
    const int w = threadIdx.x >> 6, lane = threadIdx.x & 63;
    const int r = b * 4 + w;
    const int s = offs[r], e = offs[r + 1];
    const u16* Xl = X + lane * 4;
    float a0 = 0.f, a1 = 0.f, a2 = 0.f, a3 = 0.f;
    int j = s;
    for (; j + 4 <= e; j += 4) {
        const int c0 = cols[j], c1 = cols[j + 1], c2 = cols[j + 2], c3 = cols[j + 3];
        const float v0 = vals[j], v1 = vals[j + 1], v2 = vals[j + 2], v3 = vals[j + 3];
        const ushort4 x0 = *(const ushort4*)(Xl + (size_t)c0 * DIM);
        const ushort4 x1 = *(const ushort4*)(Xl + (size_t)c1 * DIM);
        const ushort4 x2 = *(const ushort4*)(Xl + (size_t)c2 * DIM);
        const ushort4 x3 = *(const ushort4*)(Xl + (size_t)c3 * DIM);
        a0 = fmaf(v0, bf2f(x0.x), a0); a1 = fmaf(v0, bf2f(x0.y), a1);
        a2 = fmaf(v0, bf2f(x0.z), a2); a3 = fmaf(v0, bf2f(x0.w), a3);
        a0 = fmaf(v1, bf2f(x1.x), a0); a1 = fmaf(v1, bf2f(x1.y), a1);
        a2 = fmaf(v1, bf2f(x1.z), a2); a3 = fmaf(v1, bf2f(x1.w), a3);
        a0 = fmaf(v2, bf2f(x2.x), a0); a1 = fmaf(v2, bf2f(x2.y), a1);
        a2 = fmaf(v2, bf2f(x2.z), a2); a3 = fmaf(v2, bf2f(x2.w), a3);
        a0 = fmaf(v3, bf2f(x3.x), a0); a1 = fmaf(v3, bf2f(x3.y), a1);
        a2 = fmaf(v3, bf2f(x3.z), a2); a3 = fmaf(v3, bf2f(x3.w), a3);
    }
    for (; j < e; j++) {
        const int c = cols[j];
        const float v = vals[j];
        const ushort4 x = *(const ushort4*)(Xl + (size_t)c * DIM);
        a0 = fmaf(v, bf2f(x.x), a0); a1 = fmaf(v, bf2f(x.y), a1);
        a2 = fmaf(v, bf2f(x.z), a2); a3 = fmaf(v, bf2f(x.w), a3);
    }
    ushort4 o;
    o.x = f2bf(fmaxf(a0, 0.f)); o.y = f2bf(fmaxf(a1, 0.f));
    o.z = f2bf(fmaxf(a2, 0.f)); o.w = f2bf(fmaxf(a3, 0.f));
    *(ushort4*)(Y + (size_t)r * 512 + lane * 4) = o;
}

// ---------------------------------------------------------------------------
// Conversions (merged)
// ---------------------------------------------------------------------------
// 3 feature matrices f32 -> bf16 into right halves of concat buffers (ld 512)
__global__ __launch_bounds__(256) void cvt_feat3_kernel(const float* __restrict__ fq,
                                                        const float* __restrict__ fi,
                                                        const float* __restrict__ ft,
                                                        u16* __restrict__ cq, u16* __restrict__ ci,
                                                        u16* __restrict__ ct) {
    int idx = blockIdx.x * 256 + threadIdx.x;  // vec4 index
    const float* src; u16* dst;
    if (idx < NQ * 64) { src = fq; dst = cq; }
    else if ((idx -= NQ * 64) < NI * 64) { src = fi; dst = ci; }
    else { idx -= NI * 64; src = ft; dst = ct; }
    const float4 v = *(const float4*)(src + (size_t)idx * 4);
    const int r = idx >> 6, c = (idx & 63) * 4;
    ushort4 o;
    o.x = f2bf(v.x); o.y = f2bf(v.y); o.z = f2bf(v.z); o.w = f2bf(v.w);
    *(ushort4*)(dst + (size_t)r * 512 + 256 + c) = o;
}

// W^T, Q^T transposed-cvt + Wq/Wi/Wt straight cvt, all in one launch
__global__ __launch_bounds__(256) void cvt_weights_kernel(
    const float* __restrict__ W, u16* __restrict__ WTR, const float* __restrict__ Qm,
    u16* __restrict__ QTR, const float* __restrict__ Wq, u16* __restrict__ WXQ,
    const float* __restrict__ Wi, u16* __restrict__ WXI, const float* __restrict__ Wt,
    u16* __restrict__ WXT) {
    int idx = blockIdx.x * 256 + threadIdx.x;
    if (idx < DIM * DIM) {  // WTR[n*256+k] = W[k*256+n]
        int n = idx >> 8, k = idx & 255;
        WTR[idx] = f2bf(W[(size_t)k * DIM + n]);
        return;
    }
    idx -= DIM * DIM;
    if (idx < DOUT * DOUT) {  // QTR[n*128+k] = Q[k*128+n]
        int n = idx >> 7, k = idx & 127;
        QTR[idx] = f2bf(Qm[(size_t)k * DOUT + n]);
        return;
    }
    idx -= DOUT * DOUT;
    if (idx < DOUT * 512) { WXQ[idx] = f2bf(Wq[idx]); return; }
    idx -= DOUT * 512;
    if (idx < DOUT * 512) { WXI[idx] = f2bf(Wi[idx]); return; }
    idx -= DOUT * 512;
    if (idx < DOUT * 512) WXT[idx] = f2bf(Wt[idx]);
}

// ---------------------------------------------------------------------------
// bf16 NT MFMA GEMM with 3-way segment select on blockIdx.y:
// C[M,N] = A[M,K] @ B[N,K]^T. 128x128 tile, 256 threads (4 waves 2x2), BK=64,
// global_load_lds staging with row-rotation LDS k-block swizzle.
// ---------------------------------------------------------------------------
template <int OUT_BF16>
__global__ __launch_bounds__(256) void gemm_bf16_nt_seg(
    const u16* __restrict__ A0, const u16* __restrict__ A1, const u16* __restrict__ A2,
    const u16* __restrict__ B0, const u16* __restrict__ B1, const u16* __restrict__ B2,
    void* __restrict__ C0, void* __restrict__ C1, void* __restrict__ C2,
    int ldc0, int ldc1, int ldc2, int yb0, int yb1, int xb0, int xb1, int xb2,
    int K, int lda, int ldb) {
    const int by = blockIdx.y, bx = blockIdx.x;
    const u16* A; const u16* B; void* Cout; int ldc; int xb; int byl;
    if (by < yb0) { A = A0; B = B0; Cout = C0; ldc = ldc0; xb = xb0; byl = by; }
    else if (by < yb0 + yb1) { A = A1; B = B1; Cout = C1; ldc = ldc1; xb = xb1; byl = by - yb0; }
    else { A = A2; B = B2; Cout = C2; ldc = ldc2; xb = xb2; byl = by - yb0 - yb1; }
    if (bx >= xb) return;  // uniform per block, before any barrier

    __shared__ alignas(16) u16 As[128 * 64];
    __shared__ alignas(16) u16 Bs[128 * 64];
    const int tid = threadIdx.x;
    const int l = tid & 63;
    const int w = tid >> 6;
    const size_t m0 = (size_t)byl * 128;
    const size_t n0 = (size_t)bx * 128;
    const int lr = l >> 3;               // staging row-in-group 0..7
    const int skb = ((l & 7) - lr) & 7;  // global k-block this lane fetches (rotated)
    const u16* Ag = A + (m0 + (size_t)(w * 32 + lr)) * lda + skb * 8;
    const u16* Bg = B + (n0 + (size_t)(w * 32 + lr)) * ldb + skb * 8;
    u16* ldsA = As + (w * 32) * 64;
    u16* ldsB = Bs + (w * 32) * 64;

    const int fr = l & 15;  // fragment row (m or n)
    const int fq = l >> 4;  // quad 0..3
    const int wmr = (w >> 1) * 64;
    const int wnr = (w & 1) * 64;

    f32x4 acc[4][4] = {};

    for (int k0 = 0; k0 < K; k0 += 64) {
#pragma unroll
        for (int t = 0; t < 4; t++) {
            __builtin_amdgcn_global_load_lds(
                (const __attribute__((address_space(1))) void*)(Ag + (size_t)t * 8 * lda + k0),
                (__attribute__((address_space(3))) void*)(ldsA + t * 8 * 64), 16, 0, 0);
            __builtin_amdgcn_global_load_lds(
                (const __attribute__((address_space(1))) void*)(Bg + (size_t)t * 8 * ldb + k0),
                (__attribute__((address_space(3))) void*)(ldsB + t * 8 * 64), 16, 0, 0);
        }
        __syncthreads();
#pragma unroll
        for (int ks = 0; ks < 2; ks++) {
            const int kb = ks * 4 + fq;  // k-block 0..7 within BK tile
            short8 af[4], bf[4];
#pragma unroll
            for (int mt = 0; mt < 4; mt++) {
                const int r = wmr + mt * 16 + fr;
                af[mt] = *(const short8*)(As + r * 64 + ((kb + r) & 7) * 8);
            }
#pragma unroll
            for (int nt = 0; nt < 4; nt++) {
                const int r = wnr + nt * 16 + fr;
                bf[nt] = *(const short8*)(Bs + r * 64 + ((kb + r) & 7) * 8);
            }
#pragma unroll
            for (int mt = 0; mt < 4; mt++)
#pragma unroll
                for (int nt = 0; nt < 4; nt++)
                    acc[mt][nt] = __builtin_amdgcn_mfma_f32_16x16x32_bf16(af[mt], bf[nt],
                                                                          acc[mt][nt], 0, 0, 0);
        }
        __syncthreads();
    }
    // C/D layout: col = lane&15, row = (lane>>4)*4 + reg   [m89/m91 verified]
    const size_t crow = m0 + wmr + fq * 4;
    const size_t ccol = n0 + wnr + fr;
#pragma unroll
    for (int mt = 0; mt < 4; mt++)
#pragma unroll
        for (int nt = 0; nt < 4; nt++)
#pragma unroll
            for (int i = 0; i < 4; i++) {
                size_t r = crow + mt * 16 + i;
                size_t c = ccol + nt * 16;
                if (OUT_BF16)
                    ((u16*)Cout)[r * ldc + c] = f2bf(acc[mt][nt][i]);
                else
                    ((float*)Cout)[r * ldc + c] = acc[mt][nt][i];
            }
}

// ---------------------------------------------------------------------------
// BatchNorm (biased var) + ReLU. Stats: coalesced row-major partials +
// atomicAdd (STAT zeroed by memset). Apply: merged over 3 matrices.
// Linear bias cancels in BN (h - mean) and is never added.
// ---------------------------------------------------------------------------
__global__ __launch_bounds__(256) void bn_stats3_kernel(const float* __restrict__ LQ,
                                                        const float* __restrict__ LI,
                                                        const float* __restrict__ LT,
                                                        float* __restrict__ STAT) {
    const float* h; int N; float* st;
    if (blockIdx.y == 0) { h = LQ; N = NQ; st = STAT; }
    else if (blockIdx.y == 1) { h = LI; N = NI; st = STAT + 256; }
    else { h = LT; N = NTT; st = STAT + 512; }
    const int t = threadIdx.x;
    const int c = t & 127, half = t >> 7;
    const int rows = N / gridDim.x;  // grid.x = 32; N divisible
    const int r0 = blockIdx.x * rows;
    float s = 0.f, ss = 0.f;
    for (int r = r0 + half; r < r0 + rows; r += 2) {
        float v = h[(size_t)r * DOUT + c];
        s += v;
        ss += v * v;
    }
    __shared__ float buf[256];
    buf[t] = s;
    __syncthreads();
    if (half == 0) s += buf[t + 128];
    __syncthreads();
    buf[t] = ss;
    __syncthreads();
    if (half == 0) {
        ss += buf[t + 128];
        atomicAdd(&st[c], s);
        atomicAdd(&st[DOUT + c], ss);
    }
}

__global__ __launch_bounds__(256) void bn_apply3_kernel(
    const float* __restrict__ LQ, const float* __restrict__ LI, const float* __restrict__ LT,
    const float* __restrict__ STAT, const float* __restrict__ gq, const float* __restrict__ bq,
    const float* __restrict__ gi, const float* __restrict__ bi, const float* __restrict__ gt,
    const float* __restrict__ bt, u16* __restrict__ EQB, u16* __restrict__ EIB,
    u16* __restrict__ ETB) {
    size_t idx = (size_t)blockIdx.x * 256 + threadIdx.x;
    const float* h; const float* st; const float* g; const float* be; u16* o; int N;
    if (idx < (size_t)NQ * DOUT) { h = LQ; st = STAT; g = gq; be = bq; o = EQB; N = NQ; }
    else if ((idx -= (size_t)NQ * DOUT) < (size_t)NI * DOUT) {
        h = LI; st = STAT + 256; g = gi; be = bi; o = EIB; N = NI;
    } else {
        idx -= (size_t)NI * DOUT;
        h = LT; st = STAT + 512; g = gt; be = bt; o = ETB; N = NTT;
    }
    const int c = (int)(idx & (DOUT - 1));
    const float inv_n = 1.0f / (float)N;
    const float mu = st[c] * inv_n;
    const float var = st[DOUT + c] * inv_n - mu * mu;
    float v = (h[idx] - mu) * rsqrtf(var + BN_EPS) * g[c] + be[c];
    o[idx] = f2bf(fmaxf(v, 0.f));
}

// ---------------------------------------------------------------------------
// Launch
// ---------------------------------------------------------------------------
extern "C" void kernel_launch(void* const* d_in, const int* in_sizes, int n_in, void* d_out,
                              int out_size, void* d_ws, size_t ws_size, hipStream_t stream) {
    const float* feature_q = (const float*)d_in[0];
    const float* feature_i = (const float*)d_in[1];
    const float* feature_t = (const float*)d_in[2];
    const int* qi_src = (const int*)d_in[3];
    const int* qi_dst = (const int*)d_in[4];
    const float* qi_val = (const float*)d_in[5];
    const int* it_src = (const int*)d_in[6];
    const int* it_dst = (const int*)d_in[7];
    const float* it_val = (const float*)d_in[8];
    const float* W = (const float*)d_in[9];
    const float* Wq = (const float*)d_in[10];
    const float* gq = (const float*)d_in[12];
    const float* betaq = (const float*)d_in[13];
    const float* Wi = (const float*)d_in[14];
    const float* gi = (const float*)d_in[16];
    const float* betai = (const float*)d_in[17];
    const float* Wt = (const float*)d_in[18];
    const float* gt = (const float*)d_in[20];
    const float* betat = (const float*)d_in[21];
    const float* Qm = (const float*)d_in[22];
    float* out = (float*)d_out;
    char* ws = (char*)d_ws;

    u16* FQW = (u16*)(ws + BO_FQW);
    u16* FIW = (u16*)(ws + BO_FIW);
    u16* FTW = (u16*)(ws + BO_FTW);
    u16* CQ = (u16*)(ws + BO_CQ);
    u16* CI = (u16*)(ws + BO_CI);
    u16* CT = (u16*)(ws + BO_CT);
    float* LQ = (float*)(ws + BO_LQ);
    float* LI = (float*)(ws + BO_LI);
    float* LT = (float*)(ws + BO_LT);
    u16* EQB = (u16*)(ws + BO_EQB);
    u16* EIB = (u16*)(ws + BO_EIB);
    u16* ETB = (u16*)(ws + BO_ETB);
    u16* EQQ = (u16*)(ws + BO_EQQ);
    u16* EIQ = (u16*)(ws + BO_EIQ);
    u16* WTR = (u16*)(ws + BO_WTR);
    u16* WXQ = (u16*)(ws + BO_WXQ);
    u16* WXI = (u16*)(ws + BO_WXI);
    u16* WXT = (u16*)(ws + BO_WXT);
    u16* QTR = (u16*)(ws + BO_QTR);
    float* STAT = (float*)(ws + BO_STAT);
    int* Aoff = (int*)(ws + BO_AOFF); int* Acur = (int*)(ws + BO_ACUR);
    int* Acol = (int*)(ws + BO_ACOL); float* Aval = (float*)(ws + BO_AVAL);
    int* Boff = (int*)(ws + BO_BOFF); int* Bcur = (int*)(ws + BO_BCUR);
    int* Bcol = (int*)(ws + BO_BCOL); float* Bval = (float*)(ws + BO_BVAL);
    int* Doff = (int*)(ws + BO_DOFF); int* Dcur = (int*)(ws + BO_DCUR);
    int* Dcol = (int*)(ws + BO_DCOL); float* Dval = (float*)(ws + BO_DVAL);

    // ---- zero CSR counters + BN stat accumulators ----
    hipMemsetAsync(Acur, 0, NQ * sizeof(int), stream);
    hipMemsetAsync(Bcur, 0, NI * sizeof(int), stream);
    hipMemsetAsync(Dcur, 0, NTT * sizeof(int), stream);
    hipMemsetAsync(STAT, 0, 768 * sizeof(float), stream);

    // ---- conversions (2 launches) ----
    cvt_feat3_kernel<<<(NQ + NI + NTT) * 64 / 256, 256, 0, stream>>>(feature_q, feature_i,
                                                                     feature_t, CQ, CI, CT);
    cvt_weights_kernel<<<(DIM * DIM + DOUT * DOUT + 3 * DOUT * 512 + 255) / 256, 256, 0, stream>>>(
        W, WTR, Qm, QTR, Wq, WXQ, Wi, WXI, Wt, WXT);

    // ---- CSR build (3 launches) ----
    hist4_kernel<<<(2 * EQI + 2 * EIT) / 256, 256, 0, stream>>>(qi_src, EQI, Acur, qi_dst, EQI,
                                                                Bcur, it_src, EIT, Bcur, it_dst,
                                                                EIT, Dcur);
    scan3_kernel<<<3, 1024, 0, stream>>>(Acur, Aoff, Bcur, Boff, Dcur, Doff);
    {
        ScatDesc d;
        d.s0 = {qi_src, qi_dst, qi_val, EQI, 0, Acur, Acol, Aval};
        d.s1 = {qi_dst, qi_src, qi_val, EQI, 0, Bcur, Bcol, Bval};
        d.s2 = {it_src, it_dst, it_val, EIT, NQ, Bcur, Bcol, Bval};
        d.s3 = {it_dst, it_src, it_val, EIT, 0, Dcur, Dcol, Dval};
        scatter4_kernel<<<(2 * EQI + 2 * EIT) / 256, 256, 0, stream>>>(d);
    }

    // ---- projections: [fq;fi;ft] @ W in one launch (320 blocks) ----
    gemm_bf16_nt_seg<1><<<dim3(2, NQ / 128 + NI / 128 + NTT / 128), 256, 0, stream>>>(
        CQ + 256, CI + 256, CT + 256, WTR, WTR, WTR, FQW, FIW, FTW, DIM, DIM, DIM, NQ / 128,
        NI / 128, 2, 2, 2, DIM, 512, 256);

    // ---- sparse aggregations -> relu -> bf16 left halves (one launch) ----
    spmm3_kernel<<<NQ / 4 + NI / 4 + NTT / 4, 256, 0, stream>>>(
        Aoff, Acol, Aval, FIW, CQ, NQ / 4, Boff, Bcol, Bval, FQW, CI, NI / 4, Doff, Dcol, Dval,
        FIW, CT);

    // ---- concat-linear: [hidden,feat] @ Wx^T, f32 out (one launch, 160 blocks) ----
    gemm_bf16_nt_seg<0><<<dim3(1, NQ / 128 + NI / 128 + NTT / 128), 256, 0, stream>>>(
        CQ, CI, CT, WXQ, WXI, WXT, LQ, LI, LT, DOUT, DOUT, DOUT, NQ / 128, NI / 128, 1, 1, 1, 512,
        512, 512);

    // ---- BN + ReLU -> bf16 embeds (2 launches) ----
    bn_stats3_kernel<<<dim3(32, 3), 256, 0, stream>>>(LQ, LI, LT, STAT);
    bn_apply3_kernel<<<((NQ + NI + NTT) * DOUT) / 256, 256, 0, stream>>>(
        LQ, LI, LT, STAT, gq, betaq, gi, betai, gt, betat, EQB, EIB, ETB);

    // ---- embed @ Q (one launch, 128 blocks) ----
    gemm_bf16_nt_seg<1><<<dim3(1, NQ / 128 + NI / 128), 256, 0, stream>>>(
        EQB, EIB, EIB, QTR, QTR, QTR, EQQ, EIQ, EIQ, DOUT, DOUT, DOUT, NQ / 128, NI / 128, 1, 1, 1,
        DOUT, DOUT, DOUT);

    // ---- scores (one launch): qi [8192x8192] + it [8192x4096] ----
    gemm_bf16_nt_seg<0><<<dim3(NI / 128, NQ / 128 + NI / 128), 256, 0, stream>>>(
        EQQ, EIQ, EIQ, EIB, ETB, ETB, out, out + (size_t)NQ * NI, out + (size_t)NQ * NI, NI, NTT,
        NTT, NQ / 128, NI / 128, NI / 128, NTT / 128, NTT / 128, DOUT, DOUT, DOUT);
}

// Round 2
// 646.065 us; speedup vs baseline: 1.3766x; 1.0418x over previous
//
#include <hip/hip_runtime.h>
#include <stddef.h>
#include <stdint.h>

using u16 = unsigned short;
typedef __attribute__((ext_vector_type(8))) short short8;
typedef __attribute__((ext_vector_type(4))) float f32x4;

// ---------------------------------------------------------------------------
// Problem constants
// ---------------------------------------------------------------------------
constexpr int NQ = 8192, NI = 8192, NTT = 4096, DIM = 256, DOUT = 128;
constexpr int EQI = 262144, EIT = 131072, EB = EQI + EIT;
constexpr float BN_EPS = 1e-5f;

// prep kernel block partition
constexpr int NB_CVT = (NQ + NI + NTT) * 64 / 256;                          // 5120
constexpr int NB_W = (DIM * DIM + DOUT * DOUT + 3 * DOUT * 512) / 256;      // 1088
constexpr int NB_HIST = (2 * EQI + 2 * EIT) / 256;                          // 3072
constexpr int NB_SCAT = (2 * EQI + 2 * EIT) / 256;                          // 3072

// ---------------------------------------------------------------------------
// Workspace byte offsets
// ---------------------------------------------------------------------------
constexpr size_t al(size_t x) { return (x + 255) & ~(size_t)255; }
constexpr size_t BO_FQW = 0;                                   // bf16 [NQ,256]
constexpr size_t BO_FTW = BO_FQW + (size_t)NQ * DIM * 2;       // bf16 [NTT,256] (contiguous after FQW)
constexpr size_t BO_FIW = al(BO_FTW + (size_t)NTT * DIM * 2);  // bf16 [NI,256]
constexpr size_t BO_CQ  = al(BO_FIW + (size_t)NI * DIM * 2);   // bf16 [NQ,512] concat
constexpr size_t BO_CI  = al(BO_CQ + (size_t)NQ * 512 * 2);    // bf16 [NI,512]
constexpr size_t BO_CT  = al(BO_CI + (size_t)NI * 512 * 2);    // bf16 [NTT,512]
constexpr size_t BO_LQ  = al(BO_CT + (size_t)NTT * 512 * 2);   // f32  [NQ,128]
constexpr size_t BO_LI  = al(BO_LQ + (size_t)NQ * DOUT * 4);
constexpr size_t BO_LT  = al(BO_LI + (size_t)NI * DOUT * 4);
constexpr size_t BO_EQB = al(BO_LT + (size_t)NTT * DOUT * 4);  // bf16 embed_q [NQ,128]
constexpr size_t BO_EIB = al(BO_EQB + (size_t)NQ * DOUT * 2);
constexpr size_t BO_ETB = al(BO_EIB + (size_t)NI * DOUT * 2);
constexpr size_t BO_EQQ = al(BO_ETB + (size_t)NTT * DOUT * 2); // bf16 embed_q@Q [NQ,128]
constexpr size_t BO_EIQ = al(BO_EQQ + (size_t)NQ * DOUT * 2);
constexpr size_t BO_WTR = al(BO_EIQ + (size_t)NI * DOUT * 2);  // bf16 W^T [256,256]
constexpr size_t BO_WXQ = al(BO_WTR + (size_t)DIM * DIM * 2);  // bf16 Wq [128,512]
constexpr size_t BO_WXI = al(BO_WXQ + (size_t)DOUT * 512 * 2);
constexpr size_t BO_WXT = al(BO_WXI + (size_t)DOUT * 512 * 2);
constexpr size_t BO_QTR = al(BO_WXT + (size_t)DOUT * 512 * 2); // bf16 Q^T [128,128]
constexpr size_t BO_STAT = al(BO_QTR + (size_t)DOUT * DOUT * 2);  // f32 1024
constexpr size_t BO_AOFF = al(BO_STAT + 1024 * 4);
constexpr size_t BO_ACUR = al(BO_AOFF + (size_t)(NQ + 1) * 4);
constexpr size_t BO_ACOL = al(BO_ACUR + (size_t)NQ * 4);
constexpr size_t BO_AVAL = al(BO_ACOL + (size_t)EQI * 4);
constexpr size_t BO_BOFF = al(BO_AVAL + (size_t)EQI * 4);
constexpr size_t BO_BCUR = al(BO_BOFF + (size_t)(NI + 1) * 4);
constexpr size_t BO_BCOL = al(BO_BCUR + (size_t)NI * 4);
constexpr size_t BO_BVAL = al(BO_BCOL + (size_t)EB * 4);
constexpr size_t BO_DOFF = al(BO_BVAL + (size_t)EB * 4);
constexpr size_t BO_DCUR = al(BO_DOFF + (size_t)(NTT + 1) * 4);
constexpr size_t BO_DCOL = al(BO_DCUR + (size_t)NTT * 4);
constexpr size_t BO_DVAL = al(BO_DCOL + (size_t)EIT * 4);

// ---------------------------------------------------------------------------
// bf16 helpers (RNE)
// ---------------------------------------------------------------------------
__device__ __forceinline__ u16 f2bf(float f) {
    union { float f; uint32_t u; } v;
    v.f = f;
    uint32_t u = v.u;
    u += 0x7FFFu + ((u >> 16) & 1u);
    return (u16)(u >> 16);
}
__device__ __forceinline__ float bf2f(u16 h) {
    union { uint32_t u; float f; } v;
    v.u = (uint32_t)h << 16;
    return v.f;
}

// ---------------------------------------------------------------------------
// Prep mega-kernel: feature cvt (f32->bf16 right halves) + weight cvt +
// 4-segment histogram, one launch.
// ---------------------------------------------------------------------------
__global__ __launch_bounds__(256) void prep_kernel(
    const float* __restrict__ fq, const float* __restrict__ fi, const float* __restrict__ ft,
    u16* __restrict__ cq, u16* __restrict__ ci, u16* __restrict__ ct,
    const float* __restrict__ W, u16* __restrict__ WTR, const float* __restrict__ Qm,
    u16* __restrict__ QTR, const float* __restrict__ Wq, u16* __restrict__ WXQ,
    const float* __restrict__ Wi, u16* __restrict__ WXI, const float* __restrict__ Wt,
    u16* __restrict__ WXT, const int* __restrict__ qi_src, const int* __restrict__ qi_dst,
    const int* __restrict__ it_src, const int* __restrict__ it_dst, int* __restrict__ Acur,
    int* __restrict__ Bcur, int* __restrict__ Dcur) {
    int b = blockIdx.x;
    if (b < NB_CVT) {  // feature conversion, vec4 granularity
        int idx = b * 256 + threadIdx.x;
        const float* src; u16* dst;
        if (idx < NQ * 64) { src = fq; dst = cq; }
        else if ((idx -= NQ * 64) < NI * 64) { src = fi; dst = ci; }
        else { idx -= NI * 64; src = ft; dst = ct; }
        const float4 v = *(const float4*)(src + (size_t)idx * 4);
        const int r = idx >> 6, c = (idx & 63) * 4;
        ushort4 o;
        o.x = f2bf(v.x); o.y = f2bf(v.y); o.z = f2bf(v.z); o.w = f2bf(v.w);
        *(ushort4*)(dst + (size_t)r * 512 + 256 + c) = o;
        return;
    }
    b -= NB_CVT;
    if (b < NB_W) {  // weight conversions
        int idx = b * 256 + threadIdx.x;
        if (idx < DIM * DIM) {  // WTR[n*256+k] = W[k*256+n]
            int n = idx >> 8, k = idx & 255;
            WTR[idx] = f2bf(W[(size_t)k * DIM + n]);
            return;
        }
        idx -= DIM * DIM;
        if (idx < DOUT * DOUT) {  // QTR[n*128+k] = Q[k*128+n]
            int n = idx >> 7, k = idx & 127;
            QTR[idx] = f2bf(Qm[(size_t)k * DOUT + n]);
            return;
        }
        idx -= DOUT * DOUT;
        if (idx < DOUT * 512) { WXQ[idx] = f2bf(Wq[idx]); return; }
        idx -= DOUT * 512;
        if (idx < DOUT * 512) { WXI[idx] = f2bf(Wi[idx]); return; }
        idx -= DOUT * 512;
        WXT[idx] = f2bf(Wt[idx]);
        return;
    }
    b -= NB_W;  // histogram
    int idx = b * 256 + threadIdx.x;
    if (idx < EQI) { atomicAdd(&Acur[qi_src[idx]], 1); return; }
    idx -= EQI;
    if (idx < EQI) { atomicAdd(&Bcur[qi_dst[idx]], 1); return; }
    idx -= EQI;
    if (idx < EIT) { atomicAdd(&Bcur[it_src[idx]], 1); return; }
    idx -= EIT;
    atomicAdd(&Dcur[it_dst[idx]], 1);
}

// ---------------------------------------------------------------------------
// 3 exclusive scans in one launch (block 0:A/NQ, 1:B/NI, 2:D/NTT).
// Register-blocked: 8 elems/thread, single block-scan pass.
// Writes exclusive prefix into offs[0..n] and in-place into cnt (cursor).
// ---------------------------------------------------------------------------
__global__ __launch_bounds__(1024) void scan3_kernel(int* cA, int* oA, int* cB, int* oB,
                                                     int* cD, int* oD) {
    int* cnt; int* offs; int n;
    if (blockIdx.x == 0) { cnt = cA; offs = oA; n = NQ; }
    else if (blockIdx.x == 1) { cnt = cB; offs = oB; n = NI; }
    else { cnt = cD; offs = oD; n = NTT; }
    __shared__ int swv[16];
    const int t = threadIdx.x;
    const int lane = t & 63, wv = t >> 6;
    const int base = t * 8;
    int v[8];
    int run = 0;
    if (base + 8 <= n) {
        const int4 p0 = *(const int4*)(cnt + base);
        const int4 p1 = *(const int4*)(cnt + base + 4);
        int tmp[8] = {p0.x, p0.y, p0.z, p0.w, p1.x, p1.y, p1.z, p1.w};
#pragma unroll
        for (int i = 0; i < 8; i++) { run += tmp[i]; v[i] = run; }
    } else {
#pragma unroll
        for (int i = 0; i < 8; i++) {
            int x = (base + i < n) ? cnt[base + i] : 0;
            run += x;
            v[i] = run;
        }
    }
    int x = run;  // wave inclusive scan of per-thread totals
#pragma unroll
    for (int off = 1; off < 64; off <<= 1) {
        int y = __shfl_up(x, off, 64);
        if (lane >= off) x += y;
    }
    if (lane == 63) swv[wv] = x;
    __syncthreads();
    if (wv == 0 && lane < 16) {
        int ws = swv[lane];
#pragma unroll
        for (int off = 1; off < 16; off <<= 1) {
            int y = __shfl_up(ws, off, 16);
            if (lane >= off) ws += y;
        }
        swv[lane] = ws;
    }
    __syncthreads();
    const int tbase = ((wv > 0) ? swv[wv - 1] : 0) + (x - run);  // exclusive base for thread
#pragma unroll
    for (int i = 0; i < 8; i++) {
        if (base + i < n) {
            const int e = tbase + ((i > 0) ? v[i - 1] : 0);
            offs[base + i] = e;
            cnt[base + i] = e;
        }
    }
    if (t == 0) offs[n] = swv[15];
}

// ---------------------------------------------------------------------------
// Scatter descriptor
// ---------------------------------------------------------------------------
struct Scat {
    const int* key; const int* oth; const float* val;
    int E, coff;
    int* cur; int* col; float* sv;
};
struct ScatDesc { Scat s0, s1, s2, s3; };

// ---------------------------------------------------------------------------
// GEMM tile device body: C[128,128] tile of A[M,K] @ B[N,K]^T, bf16 MFMA,
// 256 threads (4 waves 2x2), BK=64, global_load_lds with row-rotation swizzle.
// ---------------------------------------------------------------------------
template <int OUT_BF16, int FUSE_STATS, int NT_STORE>
__device__ __forceinline__ void gemm_tile(const u16* __restrict__ A, const u16* __restrict__ B,
                                          void* __restrict__ Cout, int ldc, int byl, int bx,
                                          int K, int lda, int ldb, u16* As, u16* Bs,
                                          float* __restrict__ stat) {
    const int tid = threadIdx.x;
    const int l = tid & 63;
    const int w = tid >> 6;
    const size_t m0 = (size_t)byl * 128;
    const size_t n0 = (size_t)bx * 128;
    const int lr = l >> 3;               // staging row-in-group 0..7
    const int skb = ((l & 7) - lr) & 7;  // global k-block this lane fetches (rotated)
    const u16* Ag = A + (m0 + (size_t)(w * 32 + lr)) * lda + skb * 8;
    const u16* Bg = B + (n0 + (size_t)(w * 32 + lr)) * ldb + skb * 8;
    u16* ldsA = As + (w * 32) * 64;
    u16* ldsB = Bs + (w * 32) * 64;

    const int fr = l & 15;  // fragment row (m or n)
    const int fq = l >> 4;  // quad 0..3
    const int wmr = (w >> 1) * 64;
    const int wnr = (w & 1) * 64;

    f32x4 acc[4][4] = {};

    for (int k0 = 0; k0 < K; k0 += 64) {
#pragma unroll
        for (int t = 0; t < 4; t++) {
            __builtin_amdgcn_global_load_lds(
                (const __attribute__((address_space(1))) void*)(Ag + (size_t)t * 8 * lda + k0),
                (__attribute__((address_space(3))) void*)(ldsA + t * 8 * 64), 16, 0, 0);
            __builtin_amdgcn_global_load_lds(
                (const __attribute__((address_space(1))) void*)(Bg + (size_t)t * 8 * ldb + k0),
                (__attribute__((address_space(3))) void*)(ldsB + t * 8 * 64), 16, 0, 0);
        }
        __syncthreads();
#pragma unroll
        for (int ks = 0; ks < 2; ks++) {
            const int kb = ks * 4 + fq;  // k-block 0..7 within BK tile
            short8 af[4], bf[4];
#pragma unroll
            for (int mt = 0; mt < 4; mt++) {
                const int r = wmr + mt * 16 + fr;
                af[mt] = *(const short8*)(As + r * 64 + ((kb + r) & 7) * 8);
            }
#pragma unroll
            for (int nt = 0; nt < 4; nt++) {
                const int r = wnr + nt * 16 + fr;
                bf[nt] = *(const short8*)(Bs + r * 64 + ((kb + r) & 7) * 8);
            }
#pragma unroll
            for (int mt = 0; mt < 4; mt++)
#pragma unroll
                for (int nt = 0; nt < 4; nt++)
                    acc[mt][nt] = __builtin_amdgcn_mfma_f32_16x16x32_bf16(af[mt], bf[nt],
                                                                          acc[mt][nt], 0, 0, 0);
        }
        __syncthreads();
    }

    if constexpr (FUSE_STATS) {
        // Per-block column sums/sumsq into LDS (reusing As), then global atomic.
        float* csum = (float*)As;  // [128] sums, [128] sumsq
        ((float*)As)[tid] = 0.f;   // tid<256 covers both arrays
        __syncthreads();
#pragma unroll
        for (int nt = 0; nt < 4; nt++) {
            float s = 0.f, ss = 0.f;
#pragma unroll
            for (int mt = 0; mt < 4; mt++)
#pragma unroll
                for (int i = 0; i < 4; i++) {
                    const float vv = acc[mt][nt][i];
                    s += vv;
                    ss += vv * vv;
                }
            const int c = wnr + fr + nt * 16;
            atomicAdd(&csum[c], s);
            atomicAdd(&csum[DOUT + c], ss);
        }
        __syncthreads();
        if (tid < DOUT) {
            atomicAdd(&stat[tid], csum[tid]);
            atomicAdd(&stat[DOUT + tid], csum[DOUT + tid]);
        }
    }

    // C/D layout: col = lane&15, row = (lane>>4)*4 + reg   [m89/m91 verified]
    const size_t crow = m0 + wmr + fq * 4;
    const size_t ccol = n0 + wnr + fr;
#pragma unroll
    for (int mt = 0; mt < 4; mt++)
#pragma unroll
        for (int nt = 0; nt < 4; nt++)
#pragma unroll
            for (int i = 0; i < 4; i++) {
                const size_t r = crow + mt * 16 + i;
                const size_t c = ccol + nt * 16;
                if constexpr (OUT_BF16)
                    ((u16*)Cout)[r * ldc + c] = f2bf(acc[mt][nt][i]);
                else if constexpr (NT_STORE)
                    __builtin_nontemporal_store(acc[mt][nt][i], &((float*)Cout)[r * ldc + c]);
                else
                    ((float*)Cout)[r * ldc + c] = acc[mt][nt][i];
            }
}

// ---------------------------------------------------------------------------
// Merged scatter (blocks 0..NB_SCAT-1) + projection GEMM (NB_SCAT..+320).
// Scatter is atomic/latency-bound, GEMM is MFMA-bound -> they overlap.
// ---------------------------------------------------------------------------
__global__ __launch_bounds__(256) void scatter_proj_kernel(
    ScatDesc d, const u16* __restrict__ CQh, const u16* __restrict__ CIh,
    const u16* __restrict__ CTh, const u16* __restrict__ WTRp, u16* __restrict__ FQWp,
    u16* __restrict__ FIWp, u16* __restrict__ FTWp) {
    __shared__ alignas(16) u16 As[128 * 64];
    __shared__ alignas(16) u16 Bs[128 * 64];
    int b = blockIdx.x;
    if (b < NB_SCAT) {
        int idx = b * 256 + threadIdx.x;
        Scat sg;
        if (idx < d.s0.E) sg = d.s0;
        else if ((idx -= d.s0.E) < d.s1.E) sg = d.s1;
        else if ((idx -= d.s1.E) < d.s2.E) sg = d.s2;
        else { idx -= d.s2.E; sg = d.s3; }
        const int p = atomicAdd(&sg.cur[sg.key[idx]], 1);
        sg.col[p] = sg.oth[idx] + sg.coff;
        sg.sv[p] = sg.val[idx];
        return;
    }
    const int g = b - NB_SCAT;
    const int bx = g & 1, by = g >> 1;
    const u16* A; u16* C; int byl;
    if (by < NQ / 128) { A = CQh; C = FQWp; byl = by; }
    else if (by < NQ / 128 + NI / 128) { A = CIh; C = FIWp; byl = by - NQ / 128; }
    else { A = CTh; C = FTWp; byl = by - NQ / 128 - NI / 128; }
    gemm_tile<1, 0, 0>(A, WTRp, C, DIM, byl, bx, DIM, 512, DIM, As, Bs, nullptr);
}

// ---------------------------------------------------------------------------
// Segmented GEMM wrapper (3-way select on blockIdx.y)
// ---------------------------------------------------------------------------
template <int OUT_BF16, int FUSE_STATS, int NT_STORE>
__global__ __launch_bounds__(256) void gemm_seg_kernel(
    const u16* __restrict__ A0, const u16* __restrict__ A1, const u16* __restrict__ A2,
    const u16* __restrict__ B0, const u16* __restrict__ B1, const u16* __restrict__ B2,
    void* __restrict__ C0, void* __restrict__ C1, void* __restrict__ C2,
    int ldc0, int ldc1, int ldc2, int yb0, int yb1, int xb0, int xb1, int xb2,
    int K, int lda, int ldb, float* st0, float* st1, float* st2) {
    __shared__ alignas(16) u16 As[128 * 64];
    __shared__ alignas(16) u16 Bs[128 * 64];
    const int by = blockIdx.y, bx = blockIdx.x;
    const u16* A; const u16* B; void* Cout; int ldc; int xb; int byl; float* st;
    if (by < yb0) { A = A0; B = B0; Cout = C0; ldc = ldc0; xb = xb0; byl = by; st = st0; }
    else if (by < yb0 + yb1) {
        A = A1; B = B1; Cout = C1; ldc = ldc1; xb = xb1; byl = by - yb0; st = st1;
    } else {
        A = A2; B = B2; Cout = C2; ldc = ldc2; xb = xb2; byl = by - yb0 - yb1; st = st2;
    }
    if (bx >= xb) return;  // uniform per block, before any barrier
    gemm_tile<OUT_BF16, FUSE_STATS, NT_STORE>(A, B, Cout, ldc, byl, bx, K, lda, ldb, As, Bs, st);
}

// ---------------------------------------------------------------------------
// Merged CSR SPMM over 3 segments (unchanged structure, verified last round)
// ---------------------------------------------------------------------------
__global__ __launch_bounds__(256) void spmm3_kernel(
    const int* __restrict__ offs0, const int* __restrict__ cols0, const float* __restrict__ vals0,
    const u16* __restrict__ X0, u16* __restrict__ Y0, int nb0,
    const int* __restrict__ offs1, const int* __restrict__ cols1, const float* __restrict__ vals1,
    const u16* __restrict__ X1, u16* __restrict__ Y1, int nb1,
    const int* __restrict__ offs2, const int* __restrict__ cols2, const float* __restrict__ vals2,
    const u16* __restrict__ X2, u16* __restrict__ Y2) {
    int b = blockIdx.x;
    const int* offs; const int* cols; const float* vals; const u16* X; u16* Y;
    if (b < nb0) { offs = offs0; cols = cols0; vals = vals0; X = X0; Y = Y0; }
    else if ((b -= nb0) < nb1) { offs = offs1; cols = cols1; vals = vals1; X = X1; Y = Y1; }
    else { b -= nb1; offs = offs2; cols = cols2; vals = vals2; X = X2; Y = Y2; }
    const int w = threadIdx.x >> 6, lane = threadIdx.x & 63;
    const int r = b * 4 + w;
    const int s = offs[r], e = offs[r + 1];
    const u16* Xl = X + lane * 4;
    float a0 = 0.f, a1 = 0.f, a2 = 0.f, a3 = 0.f;
    int j = s;
    for (; j + 4 <= e; j += 4) {
        const int c0 = cols[j], c1 = cols[j + 1], c2 = cols[j + 2], c3 = cols[j + 3];
        const float v0 = vals[j], v1 = vals[j + 1], v2 = vals[j + 2], v3 = vals[j + 3];
        const ushort4 x0 = *(const ushort4*)(Xl + (size_t)c0 * DIM);
        const ushort4 x1 = *(const ushort4*)(Xl + (size_t)c1 * DIM);
        const ushort4 x2 = *(const ushort4*)(Xl + (size_t)c2 * DIM);
        const ushort4 x3 = *(const ushort4*)(Xl + (size_t)c3 * DIM);
        a0 = fmaf(v0, bf2f(x0.x), a0); a1 = fmaf(v0, bf2f(x0.y), a1);
        a2 = fmaf(v0, bf2f(x0.z), a2); a3 = fmaf(v0, bf2f(x0.w), a3);
        a0 = fmaf(v1, bf2f(x1.x), a0); a1 = fmaf(v1, bf2f(x1.y), a1);
        a2 = fmaf(v1, bf2f(x1.z), a2); a3 = fmaf(v1, bf2f(x1.w), a3);
        a0 = fmaf(v2, bf2f(x2.x), a0); a1 = fmaf(v2, bf2f(x2.y), a1);
        a2 = fmaf(v2, bf2f(x2.z), a2); a3 = fmaf(v2, bf2f(x2.w), a3);
        a0 = fmaf(v3, bf2f(x3.x), a0); a1 = fmaf(v3, bf2f(x3.y), a1);
        a2 = fmaf(v3, bf2f(x3.z), a2); a3 = fmaf(v3, bf2f(x3.w), a3);
    }
    for (; j < e; j++) {
        const int c = cols[j];
        const float v = vals[j];
        const ushort4 x = *(const ushort4*)(Xl + (size_t)c * DIM);
        a0 = fmaf(v, bf2f(x.x), a0); a1 = fmaf(v, bf2f(x.y), a1);
        a2 = fmaf(v, bf2f(x.z), a2); a3 = fmaf(v, bf2f(x.w), a3);
    }
    ushort4 o;
    o.x = f2bf(fmaxf(a0, 0.f)); o.y = f2bf(fmaxf(a1, 0.f));
    o.z = f2bf(fmaxf(a2, 0.f)); o.w = f2bf(fmaxf(a3, 0.f));
    *(ushort4*)(Y + (size_t)r * 512 + lane * 4) = o;
}

// ---------------------------------------------------------------------------
// BN apply (stats come from fused GEMM epilogue atomics), vectorized x4.
// Linear bias cancels in BN (h - mean) and is never added.
// ---------------------------------------------------------------------------
__global__ __launch_bounds__(256) void bn_apply3_kernel(
    const float* __restrict__ LQ, const float* __restrict__ LI, const float* __restrict__ LT,
    const float* __restrict__ STAT, const float* __restrict__ gq, const float* __restrict__ bq,
    const float* __restrict__ gi, const float* __restrict__ bi, const float* __restrict__ gt,
    const float* __restrict__ bt, u16* __restrict__ EQB, u16* __restrict__ EIB,
    u16* __restrict__ ETB) {
    size_t q4 = (size_t)blockIdx.x * 256 + threadIdx.x;  // float4 index
    const float* h; const float* st; const float* g; const float* be; u16* o; float inv_n;
    if (q4 < (size_t)NQ * 32) {
        h = LQ; st = STAT; g = gq; be = bq; o = EQB; inv_n = 1.0f / NQ;
    } else if ((q4 -= (size_t)NQ * 32) < (size_t)NI * 32) {
        h = LI; st = STAT + 256; g = gi; be = bi; o = EIB; inv_n = 1.0f / NI;
    } else {
        q4 -= (size_t)NI * 32;
        h = LT; st = STAT + 512; g = gt; be = bt; o = ETB; inv_n = 1.0f / NTT;
    }
    const float4 hv = *(const float4*)(h + q4 * 4);
    const int c0 = (int)((q4 * 4) & (DOUT - 1));
    const float r[4] = {hv.x, hv.y, hv.z, hv.w};
    u16 ov[4];
#pragma unroll
    for (int j = 0; j < 4; j++) {
        const int c = c0 + j;
        const float mu = st[c] * inv_n;
        const float var = st[DOUT + c] * inv_n - mu * mu;
        const float val = (r[j] - mu) * rsqrtf(var + BN_EPS) * g[c] + be[c];
        ov[j] = f2bf(fmaxf(val, 0.f));
    }
    ushort4 pk;
    pk.x = ov[0]; pk.y = ov[1]; pk.z = ov[2]; pk.w = ov[3];
    *(ushort4*)(o + q4 * 4) = pk;
}

// ---------------------------------------------------------------------------
// Launch
// ---------------------------------------------------------------------------
extern "C" void kernel_launch(void* const* d_in, const int* in_sizes, int n_in, void* d_out,
                              int out_size, void* d_ws, size_t ws_size, hipStream_t stream) {
    const float* feature_q = (const float*)d_in[0];
    const float* feature_i = (const float*)d_in[1];
    const float* feature_t = (const float*)d_in[2];
    const int* qi_src = (const int*)d_in[3];
    const int* qi_dst = (const int*)d_in[4];
    const float* qi_val = (const float*)d_in[5];
    const int* it_src = (const int*)d_in[6];
    const int* it_dst = (const int*)d_in[7];
    const float* it_val = (const float*)d_in[8];
    const float* W = (const float*)d_in[9];
    const float* Wq = (const float*)d_in[10];
    const float* gq = (const float*)d_in[12];
    const float* betaq = (const float*)d_in[13];
    const float* Wi = (const float*)d_in[14];
    const float* gi = (const float*)d_in[16];
    const float* betai = (const float*)d_in[17];
    const float* Wt = (const float*)d_in[18];
    const float* gt = (const float*)d_in[20];
    const float* betat = (const float*)d_in[21];
    const float* Qm = (const float*)d_in[22];
    float* out = (float*)d_out;
    char* ws = (char*)d_ws;

    u16* FQW = (u16*)(ws + BO_FQW);
    u16* FIW = (u16*)(ws + BO_FIW);
    u16* FTW = (u16*)(ws + BO_FTW);
    u16* CQ = (u16*)(ws + BO_CQ);
    u16* CI = (u16*)(ws + BO_CI);
    u16* CT = (u16*)(ws + BO_CT);
    float* LQ = (float*)(ws + BO_LQ);
    float* LI = (float*)(ws + BO_LI);
    float* LT = (float*)(ws + BO_LT);
    u16* EQB = (u16*)(ws + BO_EQB);
    u16* EIB = (u16*)(ws + BO_EIB);
    u16* ETB = (u16*)(ws + BO_ETB);
    u16* EQQ = (u16*)(ws + BO_EQQ);
    u16* EIQ = (u16*)(ws + BO_EIQ);
    u16* WTR = (u16*)(ws + BO_WTR);
    u16* WXQ = (u16*)(ws + BO_WXQ);
    u16* WXI = (u16*)(ws + BO_WXI);
    u16* WXT = (u16*)(ws + BO_WXT);
    u16* QTR = (u16*)(ws + BO_QTR);
    float* STAT = (float*)(ws + BO_STAT);
    int* Aoff = (int*)(ws + BO_AOFF); int* Acur = (int*)(ws + BO_ACUR);
    int* Acol = (int*)(ws + BO_ACOL); float* Aval = (float*)(ws + BO_AVAL);
    int* Boff = (int*)(ws + BO_BOFF); int* Bcur = (int*)(ws + BO_BCUR);
    int* Bcol = (int*)(ws + BO_BCOL); float* Bval = (float*)(ws + BO_BVAL);
    int* Doff = (int*)(ws + BO_DOFF); int* Dcur = (int*)(ws + BO_DCUR);
    int* Dcol = (int*)(ws + BO_DCOL); float* Dval = (float*)(ws + BO_DVAL);

    // ---- zero CSR counters + BN stat accumulators ----
    hipMemsetAsync(Acur, 0, NQ * sizeof(int), stream);
    hipMemsetAsync(Bcur, 0, NI * sizeof(int), stream);
    hipMemsetAsync(Dcur, 0, NTT * sizeof(int), stream);
    hipMemsetAsync(STAT, 0, 768 * sizeof(float), stream);

    // ---- prep: feature cvt + weight cvt + hist (one launch) ----
    prep_kernel<<<NB_CVT + NB_W + NB_HIST, 256, 0, stream>>>(
        feature_q, feature_i, feature_t, CQ, CI, CT, W, WTR, Qm, QTR, Wq, WXQ, Wi, WXI, Wt, WXT,
        qi_src, qi_dst, it_src, it_dst, Acur, Bcur, Dcur);

    // ---- scans ----
    scan3_kernel<<<3, 1024, 0, stream>>>(Acur, Aoff, Bcur, Boff, Dcur, Doff);

    // ---- scatter + projections overlapped in one launch ----
    {
        ScatDesc d;
        d.s0 = {qi_src, qi_dst, qi_val, EQI, 0, Acur, Acol, Aval};
        d.s1 = {qi_dst, qi_src, qi_val, EQI, 0, Bcur, Bcol, Bval};
        d.s2 = {it_src, it_dst, it_val, EIT, NQ, Bcur, Bcol, Bval};
        d.s3 = {it_dst, it_src, it_val, EIT, 0, Dcur, Dcol, Dval};
        scatter_proj_kernel<<<NB_SCAT + 2 * (NQ / 128 + NI / 128 + NTT / 128), 256, 0, stream>>>(
            d, CQ + 256, CI + 256, CT + 256, WTR, FQW, FIW, FTW);
    }

    // ---- sparse aggregations -> relu -> bf16 left halves (one launch) ----
    spmm3_kernel<<<NQ / 4 + NI / 4 + NTT / 4, 256, 0, stream>>>(
        Aoff, Acol, Aval, FIW, CQ, NQ / 4, Boff, Bcol, Bval, FQW, CI, NI / 4, Doff, Dcol, Dval,
        FIW, CT);

    // ---- concat-linear with fused BN stats: f32 out + STAT atomics ----
    gemm_seg_kernel<0, 1, 0><<<dim3(1, NQ / 128 + NI / 128 + NTT / 128), 256, 0, stream>>>(
        CQ, CI, CT, WXQ, WXI, WXT, LQ, LI, LT, DOUT, DOUT, DOUT, NQ / 128, NI / 128, 1, 1, 1, 512,
        512, 512, STAT, STAT + 256, STAT + 512);

    // ---- BN apply -> bf16 embeds ----
    bn_apply3_kernel<<<((NQ + NI + NTT) * 32) / 256, 256, 0, stream>>>(
        LQ, LI, LT, STAT, gq, betaq, gi, betai, gt, betat, EQB, EIB, ETB);

    // ---- embed @ Q (one launch) ----
    gemm_seg_kernel<1, 0, 0><<<dim3(1, NQ / 128 + NI / 128), 256, 0, stream>>>(
        EQB, EIB, EIB, QTR, QTR, QTR, EQQ, EIQ, EIQ, DOUT, DOUT, DOUT, NQ / 128, NI / 128, 1, 1, 1,
        DOUT, DOUT, DOUT, nullptr, nullptr, nullptr);

    // ---- scores (one launch, nontemporal f32 stores) ----
    gemm_seg_kernel<0, 0, 1><<<dim3(NI / 128, NQ / 128 + NI / 128), 256, 0, stream>>>(
        EQQ, EIQ, EIQ, EIB, ETB, ETB, out, out + (size_t)NQ * NI, out + (size_t)NQ * NI, NI, NTT,
        NTT, NQ / 128, NI / 128, NI / 128, NTT / 128, NTT / 128, DOUT, DOUT, DOUT, nullptr,
        nullptr, nullptr);
}

// Round 3
// 622.527 us; speedup vs baseline: 1.4286x; 1.0378x over previous
//
#include <hip/hip_runtime.h>
#include <stddef.h>
#include <stdint.h>

using u16 = unsigned short;
typedef __attribute__((ext_vector_type(8))) short short8;
typedef __attribute__((ext_vector_type(4))) float f32x4;

// ---------------------------------------------------------------------------
// Problem constants
// ---------------------------------------------------------------------------
constexpr int NQ = 8192, NI = 8192, NTT = 4096, DIM = 256, DOUT = 128;
constexpr int EQI = 262144, EIT = 131072, EB = EQI + EIT;
constexpr float BN_EPS = 1e-5f;

// prep kernel block partition
constexpr int NB_CVT = (NQ + NI + NTT) * 64 / 256;                          // 5120
constexpr int NB_W = (DIM * DIM + DOUT * DOUT + 3 * DOUT * 512) / 256;      // 1088
constexpr int NB_HIST = (2 * EQI + 2 * EIT) / 256;                          // 3072
constexpr int NB_SCAT = (2 * EQI + 2 * EIT) / 256;                          // 3072

// ---------------------------------------------------------------------------
// Workspace byte offsets
// ---------------------------------------------------------------------------
constexpr size_t al(size_t x) { return (x + 255) & ~(size_t)255; }
constexpr size_t BO_FQW = 0;                                   // bf16 [NQ,256]
constexpr size_t BO_FTW = BO_FQW + (size_t)NQ * DIM * 2;       // bf16 [NTT,256] (contiguous after FQW)
constexpr size_t BO_FIW = al(BO_FTW + (size_t)NTT * DIM * 2);  // bf16 [NI,256]
constexpr size_t BO_CQ  = al(BO_FIW + (size_t)NI * DIM * 2);   // bf16 [NQ,512] concat
constexpr size_t BO_CI  = al(BO_CQ + (size_t)NQ * 512 * 2);    // bf16 [NI,512]
constexpr size_t BO_CT  = al(BO_CI + (size_t)NI * 512 * 2);    // bf16 [NTT,512]
constexpr size_t BO_LQ  = al(BO_CT + (size_t)NTT * 512 * 2);   // f32  [NQ,128]
constexpr size_t BO_LI  = al(BO_LQ + (size_t)NQ * DOUT * 4);
constexpr size_t BO_LT  = al(BO_LI + (size_t)NI * DOUT * 4);
constexpr size_t BO_EQB = al(BO_LT + (size_t)NTT * DOUT * 4);  // bf16 embed_q [NQ,128]
constexpr size_t BO_EIB = al(BO_EQB + (size_t)NQ * DOUT * 2);
constexpr size_t BO_ETB = al(BO_EIB + (size_t)NI * DOUT * 2);
constexpr size_t BO_EQQ = al(BO_ETB + (size_t)NTT * DOUT * 2); // bf16 embed_q@Q [NQ,128]
constexpr size_t BO_EIQ = al(BO_EQQ + (size_t)NQ * DOUT * 2);
constexpr size_t BO_WTR = al(BO_EIQ + (size_t)NI * DOUT * 2);  // bf16 W^T [256,256]
constexpr size_t BO_WXQ = al(BO_WTR + (size_t)DIM * DIM * 2);  // bf16 Wq [128,512]
constexpr size_t BO_WXI = al(BO_WXQ + (size_t)DOUT * 512 * 2);
constexpr size_t BO_WXT = al(BO_WXI + (size_t)DOUT * 512 * 2);
constexpr size_t BO_QTR = al(BO_WXT + (size_t)DOUT * 512 * 2); // bf16 Q^T [128,128]
constexpr size_t BO_STAT = al(BO_QTR + (size_t)DOUT * DOUT * 2);  // f32 1024
constexpr size_t BO_AOFF = al(BO_STAT + 1024 * 4);
constexpr size_t BO_ACUR = al(BO_AOFF + (size_t)(NQ + 1) * 4);
constexpr size_t BO_ACOL = al(BO_ACUR + (size_t)NQ * 4);
constexpr size_t BO_AVAL = al(BO_ACOL + (size_t)EQI * 4);
constexpr size_t BO_BOFF = al(BO_AVAL + (size_t)EQI * 4);
constexpr size_t BO_BCUR = al(BO_BOFF + (size_t)(NI + 1) * 4);
constexpr size_t BO_BCOL = al(BO_BCUR + (size_t)NI * 4);
constexpr size_t BO_BVAL = al(BO_BCOL + (size_t)EB * 4);
constexpr size_t BO_DOFF = al(BO_BVAL + (size_t)EB * 4);
constexpr size_t BO_DCUR = al(BO_DOFF + (size_t)(NTT + 1) * 4);
constexpr size_t BO_DCOL = al(BO_DCUR + (size_t)NTT * 4);
constexpr size_t BO_DVAL = al(BO_DCOL + (size_t)EIT * 4);

// ---------------------------------------------------------------------------
// bf16 helpers (RNE)
// ---------------------------------------------------------------------------
__device__ __forceinline__ u16 f2bf(float f) {
    union { float f; uint32_t u; } v;
    v.f = f;
    uint32_t u = v.u;
    u += 0x7FFFu + ((u >> 16) & 1u);
    return (u16)(u >> 16);
}
__device__ __forceinline__ float bf2f(u16 h) {
    union { uint32_t u; float f; } v;
    v.u = (uint32_t)h << 16;
    return v.f;
}

// ---------------------------------------------------------------------------
// Prep mega-kernel: feature cvt (f32->bf16 right halves) + weight cvt +
// 4-segment histogram, one launch.
// ---------------------------------------------------------------------------
__global__ __launch_bounds__(256) void prep_kernel(
    const float* __restrict__ fq, const float* __restrict__ fi, const float* __restrict__ ft,
    u16* __restrict__ cq, u16* __restrict__ ci, u16* __restrict__ ct,
    const float* __restrict__ W, u16* __restrict__ WTR, const float* __restrict__ Qm,
    u16* __restrict__ QTR, const float* __restrict__ Wq, u16* __restrict__ WXQ,
    const float* __restrict__ Wi, u16* __restrict__ WXI, const float* __restrict__ Wt,
    u16* __restrict__ WXT, const int* __restrict__ qi_src, const int* __restrict__ qi_dst,
    const int* __restrict__ it_src, const int* __restrict__ it_dst, int* __restrict__ Acur,
    int* __restrict__ Bcur, int* __restrict__ Dcur) {
    int b = blockIdx.x;
    if (b < NB_CVT) {  // feature conversion, vec4 granularity
        int idx = b * 256 + threadIdx.x;
        const float* src; u16* dst;
        if (idx < NQ * 64) { src = fq; dst = cq; }
        else if ((idx -= NQ * 64) < NI * 64) { src = fi; dst = ci; }
        else { idx -= NI * 64; src = ft; dst = ct; }
        const float4 v = *(const float4*)(src + (size_t)idx * 4);
        const int r = idx >> 6, c = (idx & 63) * 4;
        ushort4 o;
        o.x = f2bf(v.x); o.y = f2bf(v.y); o.z = f2bf(v.z); o.w = f2bf(v.w);
        *(ushort4*)(dst + (size_t)r * 512 + 256 + c) = o;
        return;
    }
    b -= NB_CVT;
    if (b < NB_W) {  // weight conversions
        int idx = b * 256 + threadIdx.x;
        if (idx < DIM * DIM) {  // WTR[n*256+k] = W[k*256+n]
            int n = idx >> 8, k = idx & 255;
            WTR[idx] = f2bf(W[(size_t)k * DIM + n]);
            return;
        }
        idx -= DIM * DIM;
        if (idx < DOUT * DOUT) {  // QTR[n*128+k] = Q[k*128+n]
            int n = idx >> 7, k = idx & 127;
            QTR[idx] = f2bf(Qm[(size_t)k * DOUT + n]);
            return;
        }
        idx -= DOUT * DOUT;
        if (idx < DOUT * 512) { WXQ[idx] = f2bf(Wq[idx]); return; }
        idx -= DOUT * 512;
        if (idx < DOUT * 512) { WXI[idx] = f2bf(Wi[idx]); return; }
        idx -= DOUT * 512;
        WXT[idx] = f2bf(Wt[idx]);
        return;
    }
    b -= NB_W;  // histogram
    int idx = b * 256 + threadIdx.x;
    if (idx < EQI) { atomicAdd(&Acur[qi_src[idx]], 1); return; }
    idx -= EQI;
    if (idx < EQI) { atomicAdd(&Bcur[qi_dst[idx]], 1); return; }
    idx -= EQI;
    if (idx < EIT) { atomicAdd(&Bcur[it_src[idx]], 1); return; }
    idx -= EIT;
    atomicAdd(&Dcur[it_dst[idx]], 1);
}

// ---------------------------------------------------------------------------
// 3 exclusive scans in one launch (block 0:A/NQ, 1:B/NI, 2:D/NTT).
// Register-blocked: 8 elems/thread, single block-scan pass.
// ---------------------------------------------------------------------------
__global__ __launch_bounds__(1024) void scan3_kernel(int* cA, int* oA, int* cB, int* oB,
                                                     int* cD, int* oD) {
    int* cnt; int* offs; int n;
    if (blockIdx.x == 0) { cnt = cA; offs = oA; n = NQ; }
    else if (blockIdx.x == 1) { cnt = cB; offs = oB; n = NI; }
    else { cnt = cD; offs = oD; n = NTT; }
    __shared__ int swv[16];
    const int t = threadIdx.x;
    const int lane = t & 63, wv = t >> 6;
    const int base = t * 8;
    int v[8];
    int run = 0;
    if (base + 8 <= n) {
        const int4 p0 = *(const int4*)(cnt + base);
        const int4 p1 = *(const int4*)(cnt + base + 4);
        int tmp[8] = {p0.x, p0.y, p0.z, p0.w, p1.x, p1.y, p1.z, p1.w};
#pragma unroll
        for (int i = 0; i < 8; i++) { run += tmp[i]; v[i] = run; }
    } else {
#pragma unroll
        for (int i = 0; i < 8; i++) {
            int x = (base + i < n) ? cnt[base + i] : 0;
            run += x;
            v[i] = run;
        }
    }
    int x = run;  // wave inclusive scan of per-thread totals
#pragma unroll
    for (int off = 1; off < 64; off <<= 1) {
        int y = __shfl_up(x, off, 64);
        if (lane >= off) x += y;
    }
    if (lane == 63) swv[wv] = x;
    __syncthreads();
    if (wv == 0 && lane < 16) {
        int ws = swv[lane];
#pragma unroll
        for (int off = 1; off < 16; off <<= 1) {
            int y = __shfl_up(ws, off, 16);
            if (lane >= off) ws += y;
        }
        swv[lane] = ws;
    }
    __syncthreads();
    const int tbase = ((wv > 0) ? swv[wv - 1] : 0) + (x - run);  // exclusive base for thread
#pragma unroll
    for (int i = 0; i < 8; i++) {
        if (base + i < n) {
            const int e = tbase + ((i > 0) ? v[i - 1] : 0);
            offs[base + i] = e;
            cnt[base + i] = e;
        }
    }
    if (t == 0) offs[n] = swv[15];
}

// ---------------------------------------------------------------------------
// Scatter descriptor
// ---------------------------------------------------------------------------
struct Scat {
    const int* key; const int* oth; const float* val;
    int E, coff;
    int* cur; int* col; float* sv;
};
struct ScatDesc { Scat s0, s1, s2, s3; };

// ---------------------------------------------------------------------------
// GEMM tile device body: C[128,128] tile of A[M,K] @ B[N,K]^T, bf16 MFMA,
// 256 threads (4 waves 2x2), BK=64, global_load_lds with row-rotation swizzle.
// f32 output path: per-wave LDS-transposed epilogue -> global_store_dwordx4.
// ---------------------------------------------------------------------------
template <int OUT_BF16, int FUSE_STATS, int NT_STORE>
__device__ __forceinline__ void gemm_tile(const u16* __restrict__ A, const u16* __restrict__ B,
                                          void* __restrict__ Cout, int ldc, int byl, int bx,
                                          int K, int lda, int ldb, u16* SMEM,
                                          float* __restrict__ stat) {
    u16* As = SMEM;
    u16* Bs = SMEM + 128 * 64;
    const int tid = threadIdx.x;
    const int l = tid & 63;
    const int w = tid >> 6;
    const size_t m0 = (size_t)byl * 128;
    const size_t n0 = (size_t)bx * 128;
    const int lr = l >> 3;               // staging row-in-group 0..7
    const int skb = ((l & 7) - lr) & 7;  // global k-block this lane fetches (rotated)
    const u16* Ag = A + (m0 + (size_t)(w * 32 + lr)) * lda + skb * 8;
    const u16* Bg = B + (n0 + (size_t)(w * 32 + lr)) * ldb + skb * 8;
    u16* ldsA = As + (w * 32) * 64;
    u16* ldsB = Bs + (w * 32) * 64;

    const int fr = l & 15;  // fragment row (m or n)
    const int fq = l >> 4;  // quad 0..3
    const int wmr = (w >> 1) * 64;
    const int wnr = (w & 1) * 64;

    f32x4 acc[4][4] = {};

    for (int k0 = 0; k0 < K; k0 += 64) {
#pragma unroll
        for (int t = 0; t < 4; t++) {
            __builtin_amdgcn_global_load_lds(
                (const __attribute__((address_space(1))) void*)(Ag + (size_t)t * 8 * lda + k0),
                (__attribute__((address_space(3))) void*)(ldsA + t * 8 * 64), 16, 0, 0);
            __builtin_amdgcn_global_load_lds(
                (const __attribute__((address_space(1))) void*)(Bg + (size_t)t * 8 * ldb + k0),
                (__attribute__((address_space(3))) void*)(ldsB + t * 8 * 64), 16, 0, 0);
        }
        __syncthreads();
#pragma unroll
        for (int ks = 0; ks < 2; ks++) {
            const int kb = ks * 4 + fq;  // k-block 0..7 within BK tile
            short8 af[4], bf[4];
#pragma unroll
            for (int mt = 0; mt < 4; mt++) {
                const int r = wmr + mt * 16 + fr;
                af[mt] = *(const short8*)(As + r * 64 + ((kb + r) & 7) * 8);
            }
#pragma unroll
            for (int nt = 0; nt < 4; nt++) {
                const int r = wnr + nt * 16 + fr;
                bf[nt] = *(const short8*)(Bs + r * 64 + ((kb + r) & 7) * 8);
            }
#pragma unroll
            for (int mt = 0; mt < 4; mt++)
#pragma unroll
                for (int nt = 0; nt < 4; nt++)
                    acc[mt][nt] = __builtin_amdgcn_mfma_f32_16x16x32_bf16(af[mt], bf[nt],
                                                                          acc[mt][nt], 0, 0, 0);
        }
        __syncthreads();
    }

    if constexpr (FUSE_STATS) {
        // Per-block column sums/sumsq into LDS (reusing As), then global atomic.
        float* csum = (float*)As;  // [128] sums, [128] sumsq
        ((float*)As)[tid] = 0.f;   // tid<256 covers both arrays
        __syncthreads();
#pragma unroll
        for (int nt = 0; nt < 4; nt++) {
            float s = 0.f, ss = 0.f;
#pragma unroll
            for (int mt = 0; mt < 4; mt++)
#pragma unroll
                for (int i = 0; i < 4; i++) {
                    const float vv = acc[mt][nt][i];
                    s += vv;
                    ss += vv * vv;
                }
            const int c = wnr + fr + nt * 16;
            atomicAdd(&csum[c], s);
            atomicAdd(&csum[DOUT + c], ss);
        }
        __syncthreads();
        if (tid < DOUT) {
            atomicAdd(&stat[tid], csum[tid]);
            atomicAdd(&stat[DOUT + tid], csum[DOUT + tid]);
        }
        __syncthreads();  // csum region reused by transpose epilogue below
    }

    // C/D layout: col = lane&15, row = (lane>>4)*4 + reg   [m89/m91 verified]
    if constexpr (OUT_BF16) {
        const size_t crow = m0 + wmr + fq * 4;
        const size_t ccol = n0 + wnr + fr;
#pragma unroll
        for (int mt = 0; mt < 4; mt++)
#pragma unroll
            for (int nt = 0; nt < 4; nt++)
#pragma unroll
                for (int i = 0; i < 4; i++) {
                    const size_t r = crow + mt * 16 + i;
                    const size_t c = ccol + nt * 16;
                    ((u16*)Cout)[r * ldc + c] = f2bf(acc[mt][nt][i]);
                }
    } else {
        // f32: per-wave LDS-transposed epilogue. Each wave owns an 8 KB f32
        // slice (32 rows x 64 cols) of the unified 32 KB SMEM; two passes
        // cover its 64x64 quadrant. Bit-identical values, vectorized stores.
        float* S = (float*)(SMEM) + w * 2048;  // 8 KB per wave
#pragma unroll
        for (int p = 0; p < 2; p++) {
#pragma unroll
            for (int mh = 0; mh < 2; mh++) {  // mt = 2p + mh
                const int mt = 2 * p + mh;
#pragma unroll
                for (int nt = 0; nt < 4; nt++)
#pragma unroll
                    for (int i = 0; i < 4; i++)
                        S[(mh * 16 + fq * 4 + i) * 64 + nt * 16 + fr] = acc[mt][nt][i];
            }
            __syncthreads();
#pragma unroll
            for (int it = 0; it < 8; it++) {
                const int lrr = (l >> 4) + it * 4;
                const f32x4 vv = *(const f32x4*)(S + lrr * 64 + (l & 15) * 4);
                float* dst =
                    (float*)Cout + (m0 + wmr + p * 32 + lrr) * (size_t)ldc + n0 + wnr + (l & 15) * 4;
                if constexpr (NT_STORE)
                    __builtin_nontemporal_store(vv, (f32x4*)dst);
                else
                    *(f32x4*)dst = vv;
            }
            if (p == 0) __syncthreads();
        }
    }
}

// ---------------------------------------------------------------------------
// Merged scatter (blocks 0..NB_SCAT-1) + projection GEMM (NB_SCAT..+320).
// Scatter is atomic/latency-bound, GEMM is MFMA-bound -> they overlap.
// ---------------------------------------------------------------------------
__global__ __launch_bounds__(256) void scatter_proj_kernel(
    ScatDesc d, const u16* __restrict__ CQh, const u16* __restrict__ CIh,
    const u16* __restrict__ CTh, const u16* __restrict__ WTRp, u16* __restrict__ FQWp,
    u16* __restrict__ FIWp, u16* __restrict__ FTWp) {
    __shared__ alignas(16) u16 SMEM[2 * 128 * 64];
    int b = blockIdx.x;
    if (b < NB_SCAT) {
        int idx = b * 256 + threadIdx.x;
        Scat sg;
        if (idx < d.s0.E) sg = d.s0;
        else if ((idx -= d.s0.E) < d.s1.E) sg = d.s1;
        else if ((idx -= d.s1.E) < d.s2.E) sg = d.s2;
        else { idx -= d.s2.E; sg = d.s3; }
        const int p = atomicAdd(&sg.cur[sg.key[idx]], 1);
        sg.col[p] = sg.oth[idx] + sg.coff;
        sg.sv[p] = sg.val[idx];
        return;
    }
    const int g = b - NB_SCAT;
    const int bx = g & 1, by = g >> 1;
    const u16* A; u16* C; int byl;
    if (by < NQ / 128) { A = CQh; C = FQWp; byl = by; }
    else if (by < NQ / 128 + NI / 128) { A = CIh; C = FIWp; byl = by - NQ / 128; }
    else { A = CTh; C = FTWp; byl = by - NQ / 128 - NI / 128; }
    gemm_tile<1, 0, 0>(A, WTRp, C, DIM, byl, bx, DIM, 512, DIM, SMEM, nullptr);
}

// ---------------------------------------------------------------------------
// Segmented GEMM wrapper (3-way select on blockIdx.y)
// ---------------------------------------------------------------------------
template <int OUT_BF16, int FUSE_STATS, int NT_STORE>
__global__ __launch_bounds__(256) void gemm_seg_kernel(
    const u16* __restrict__ A0, const u16* __restrict__ A1, const u16* __restrict__ A2,
    const u16* __restrict__ B0, const u16* __restrict__ B1, const u16* __restrict__ B2,
    void* __restrict__ C0, void* __restrict__ C1, void* __restrict__ C2,
    int ldc0, int ldc1, int ldc2, int yb0, int yb1, int xb0, int xb1, int xb2,
    int K, int lda, int ldb, float* st0, float* st1, float* st2) {
    __shared__ alignas(16) u16 SMEM[2 * 128 * 64];
    const int by = blockIdx.y, bx = blockIdx.x;
    const u16* A; const u16* B; void* Cout; int ldc; int xb; int byl; float* st;
    if (by < yb0) { A = A0; B = B0; Cout = C0; ldc = ldc0; xb = xb0; byl = by; st = st0; }
    else if (by < yb0 + yb1) {
        A = A1; B = B1; Cout = C1; ldc = ldc1; xb = xb1; byl = by - yb0; st = st1;
    } else {
        A = A2; B = B2; Cout = C2; ldc = ldc2; xb = xb2; byl = by - yb0 - yb1; st = st2;
    }
    if (bx >= xb) return;  // uniform per block, before any barrier
    gemm_tile<OUT_BF16, FUSE_STATS, NT_STORE>(A, B, Cout, ldc, byl, bx, K, lda, ldb, SMEM, st);
}

// ---------------------------------------------------------------------------
// Merged CSR SPMM over 3 segments. One wave per row; lane owns 4 consecutive
// bf16 (8B gather -> 512B/edge per wave instr). 8-edge software pipeline for
// L3-latency hiding. Per-element accumulation order: ascending j (unchanged).
// ---------------------------------------------------------------------------
__global__ __launch_bounds__(256) void spmm3_kernel(
    const int* __restrict__ offs0, const int* __restrict__ cols0, const float* __restrict__ vals0,
    const u16* __restrict__ X0, u16* __restrict__ Y0, int nb0,
    const int* __restrict__ offs1, const int* __restrict__ cols1, const float* __restrict__ vals1,
    const u16* __restrict__ X1, u16* __restrict__ Y1, int nb1,
    const int* __restrict__ offs2, const int* __restrict__ cols2, const float* __restrict__ vals2,
    const u16* __restrict__ X2, u16* __restrict__ Y2) {
    int b = blockIdx.x;
    const int* offs; const int* cols; const float* vals; const u16* X; u16* Y;
    if (b < nb0) { offs = offs0; cols = cols0; vals = vals0; X = X0; Y = Y0; }
    else if ((b -= nb0) < nb1) { offs = offs1; cols = cols1; vals = vals1; X = X1; Y = Y1; }
    else { b -= nb1; offs = offs2; cols = cols2; vals = vals2; X = X2; Y = Y2; }
    const int w = threadIdx.x >> 6, lane = threadIdx.x & 63;
    const int r = b * 4 + w;
    const int s = offs[r], e = offs[r + 1];
    const u16* Xl = X + lane * 4;
    float a0 = 0.f, a1 = 0.f, a2 = 0.f, a3 = 0.f;
    int j = s;
    for (; j + 8 <= e; j += 8) {
        int c[8];
        float v[8];
        ushort4 x[8];
#pragma unroll
        for (int q = 0; q < 8; q++) c[q] = cols[j + q];
#pragma unroll
        for (int q = 0; q < 8; q++) v[q] = vals[j + q];
#pragma unroll
        for (int q = 0; q < 8; q++) x[q] = *(const ushort4*)(Xl + (size_t)c[q] * DIM);
#pragma unroll
        for (int q = 0; q < 8; q++) {
            a0 = fmaf(v[q], bf2f(x[q].x), a0);
            a1 = fmaf(v[q], bf2f(x[q].y), a1);
            a2 = fmaf(v[q], bf2f(x[q].z), a2);
            a3 = fmaf(v[q], bf2f(x[q].w), a3);
        }
    }
    for (; j < e; j++) {
        const int c = cols[j];
        const float v = vals[j];
        const ushort4 x = *(const ushort4*)(Xl + (size_t)c * DIM);
        a0 = fmaf(v, bf2f(x.x), a0); a1 = fmaf(v, bf2f(x.y), a1);
        a2 = fmaf(v, bf2f(x.z), a2); a3 = fmaf(v, bf2f(x.w), a3);
    }
    ushort4 o;
    o.x = f2bf(fmaxf(a0, 0.f)); o.y = f2bf(fmaxf(a1, 0.f));
    o.z = f2bf(fmaxf(a2, 0.f)); o.w = f2bf(fmaxf(a3, 0.f));
    *(ushort4*)(Y + (size_t)r * 512 + lane * 4) = o;
}

// ---------------------------------------------------------------------------
// BN apply (stats come from fused GEMM epilogue atomics), vectorized x4.
// Linear bias cancels in BN (h - mean) and is never added.
// ---------------------------------------------------------------------------
__global__ __launch_bounds__(256) void bn_apply3_kernel(
    const float* __restrict__ LQ, const float* __restrict__ LI, const float* __restrict__ LT,
    const float* __restrict__ STAT, const float* __restrict__ gq, const float* __restrict__ bq,
    const float* __restrict__ gi, const float* __restrict__ bi, const float* __restrict__ gt,
    const float* __restrict__ bt, u16* __restrict__ EQB, u16* __restrict__ EIB,
    u16* __restrict__ ETB) {
    size_t q4 = (size_t)blockIdx.x * 256 + threadIdx.x;  // float4 index
    const float* h; const float* st; const float* g; const float* be; u16* o; float inv_n;
    if (q4 < (size_t)NQ * 32) {
        h = LQ; st = STAT; g = gq; be = bq; o = EQB; inv_n = 1.0f / NQ;
    } else if ((q4 -= (size_t)NQ * 32) < (size_t)NI * 32) {
        h = LI; st = STAT + 256; g = gi; be = bi; o = EIB; inv_n = 1.0f / NI;
    } else {
        q4 -= (size_t)NI * 32;
        h = LT; st = STAT + 512; g = gt; be = bt; o = ETB; inv_n = 1.0f / NTT;
    }
    const float4 hv = *(const float4*)(h + q4 * 4);
    const int c0 = (int)((q4 * 4) & (DOUT - 1));
    const float r[4] = {hv.x, hv.y, hv.z, hv.w};
    u16 ov[4];
#pragma unroll
    for (int j = 0; j < 4; j++) {
        const int c = c0 + j;
        const float mu = st[c] * inv_n;
        const float var = st[DOUT + c] * inv_n - mu * mu;
        const float val = (r[j] - mu) * rsqrtf(var + BN_EPS) * g[c] + be[c];
        ov[j] = f2bf(fmaxf(val, 0.f));
    }
    ushort4 pk;
    pk.x = ov[0]; pk.y = ov[1]; pk.z = ov[2]; pk.w = ov[3];
    *(ushort4*)(o + q4 * 4) = pk;
}

// ---------------------------------------------------------------------------
// Launch
// ---------------------------------------------------------------------------
extern "C" void kernel_launch(void* const* d_in, const int* in_sizes, int n_in, void* d_out,
                              int out_size, void* d_ws, size_t ws_size, hipStream_t stream) {
    const float* feature_q = (const float*)d_in[0];
    const float* feature_i = (const float*)d_in[1];
    const float* feature_t = (const float*)d_in[2];
    const int* qi_src = (const int*)d_in[3];
    const int* qi_dst = (const int*)d_in[4];
    const float* qi_val = (const float*)d_in[5];
    const int* it_src = (const int*)d_in[6];
    const int* it_dst = (const int*)d_in[7];
    const float* it_val = (const float*)d_in[8];
    const float* W = (const float*)d_in[9];
    const float* Wq = (const float*)d_in[10];
    const float* gq = (const float*)d_in[12];
    const float* betaq = (const float*)d_in[13];
    const float* Wi = (const float*)d_in[14];
    const float* gi = (const float*)d_in[16];
    const float* betai = (const float*)d_in[17];
    const float* Wt = (const float*)d_in[18];
    const float* gt = (const float*)d_in[20];
    const float* betat = (const float*)d_in[21];
    const float* Qm = (const float*)d_in[22];
    float* out = (float*)d_out;
    char* ws = (char*)d_ws;

    u16* FQW = (u16*)(ws + BO_FQW);
    u16* FIW = (u16*)(ws + BO_FIW);
    u16* FTW = (u16*)(ws + BO_FTW);
    u16* CQ = (u16*)(ws + BO_CQ);
    u16* CI = (u16*)(ws + BO_CI);
    u16* CT = (u16*)(ws + BO_CT);
    float* LQ = (float*)(ws + BO_LQ);
    float* LI = (float*)(ws + BO_LI);
    float* LT = (float*)(ws + BO_LT);
    u16* EQB = (u16*)(ws + BO_EQB);
    u16* EIB = (u16*)(ws + BO_EIB);
    u16* ETB = (u16*)(ws + BO_ETB);
    u16* EQQ = (u16*)(ws + BO_EQQ);
    u16* EIQ = (u16*)(ws + BO_EIQ);
    u16* WTR = (u16*)(ws + BO_WTR);
    u16* WXQ = (u16*)(ws + BO_WXQ);
    u16* WXI = (u16*)(ws + BO_WXI);
    u16* WXT = (u16*)(ws + BO_WXT);
    u16* QTR = (u16*)(ws + BO_QTR);
    float* STAT = (float*)(ws + BO_STAT);
    int* Aoff = (int*)(ws + BO_AOFF); int* Acur = (int*)(ws + BO_ACUR);
    int* Acol = (int*)(ws + BO_ACOL); float* Aval = (float*)(ws + BO_AVAL);
    int* Boff = (int*)(ws + BO_BOFF); int* Bcur = (int*)(ws + BO_BCUR);
    int* Bcol = (int*)(ws + BO_BCOL); float* Bval = (float*)(ws + BO_BVAL);
    int* Doff = (int*)(ws + BO_DOFF); int* Dcur = (int*)(ws + BO_DCUR);
    int* Dcol = (int*)(ws + BO_DCOL); float* Dval = (float*)(ws + BO_DVAL);

    // ---- zero CSR counters + BN stat accumulators ----
    hipMemsetAsync(Acur, 0, NQ * sizeof(int), stream);
    hipMemsetAsync(Bcur, 0, NI * sizeof(int), stream);
    hipMemsetAsync(Dcur, 0, NTT * sizeof(int), stream);
    hipMemsetAsync(STAT, 0, 768 * sizeof(float), stream);

    // ---- prep: feature cvt + weight cvt + hist (one launch) ----
    prep_kernel<<<NB_CVT + NB_W + NB_HIST, 256, 0, stream>>>(
        feature_q, feature_i, feature_t, CQ, CI, CT, W, WTR, Qm, QTR, Wq, WXQ, Wi, WXI, Wt, WXT,
        qi_src, qi_dst, it_src, it_dst, Acur, Bcur, Dcur);

    // ---- scans ----
    scan3_kernel<<<3, 1024, 0, stream>>>(Acur, Aoff, Bcur, Boff, Dcur, Doff);

    // ---- scatter + projections overlapped in one launch ----
    {
        ScatDesc d;
        d.s0 = {qi_src, qi_dst, qi_val, EQI, 0, Acur, Acol, Aval};
        d.s1 = {qi_dst, qi_src, qi_val, EQI, 0, Bcur, Bcol, Bval};
        d.s2 = {it_src, it_dst, it_val, EIT, NQ, Bcur, Bcol, Bval};
        d.s3 = {it_dst, it_src, it_val, EIT, 0, Dcur, Dcol, Dval};
        scatter_proj_kernel<<<NB_SCAT + 2 * (NQ / 128 + NI / 128 + NTT / 128), 256, 0, stream>>>(
            d, CQ + 256, CI + 256, CT + 256, WTR, FQW, FIW, FTW);
    }

    // ---- sparse aggregations -> relu -> bf16 left halves (one launch) ----
    spmm3_kernel<<<NQ / 4 + NI / 4 + NTT / 4, 256, 0, stream>>>(
        Aoff, Acol, Aval, FIW, CQ, NQ / 4, Boff, Bcol, Bval, FQW, CI, NI / 4, Doff, Dcol, Dval,
        FIW, CT);

    // ---- concat-linear with fused BN stats: f32 out (cached) + STAT atomics ----
    gemm_seg_kernel<0, 1, 0><<<dim3(1, NQ / 128 + NI / 128 + NTT / 128), 256, 0, stream>>>(
        CQ, CI, CT, WXQ, WXI, WXT, LQ, LI, LT, DOUT, DOUT, DOUT, NQ / 128, NI / 128, 1, 1, 1, 512,
        512, 512, STAT, STAT + 256, STAT + 512);

    // ---- BN apply -> bf16 embeds ----
    bn_apply3_kernel<<<((NQ + NI + NTT) * 32) / 256, 256, 0, stream>>>(
        LQ, LI, LT, STAT, gq, betaq, gi, betai, gt, betat, EQB, EIB, ETB);

    // ---- embed @ Q (one launch) ----
    gemm_seg_kernel<1, 0, 0><<<dim3(1, NQ / 128 + NI / 128), 256, 0, stream>>>(
        EQB, EIB, EIB, QTR, QTR, QTR, EQQ, EIQ, EIQ, DOUT, DOUT, DOUT, NQ / 128, NI / 128, 1, 1, 1,
        DOUT, DOUT, DOUT, nullptr, nullptr, nullptr);

    // ---- scores (one launch, LDS-transposed vectorized NT stores) ----
    gemm_seg_kernel<0, 0, 1><<<dim3(NI / 128, NQ / 128 + NI / 128), 256, 0, stream>>>(
        EQQ, EIQ, EIQ, EIB, ETB, ETB, out, out + (size_t)NQ * NI, out + (size_t)NQ * NI, NI, NTT,
        NTT, NQ / 128, NI / 128, NI / 128, NTT / 128, NTT / 128, DOUT, DOUT, DOUT, nullptr,
        nullptr, nullptr);
}